// Round 2
// baseline (380.197 us; speedup 1.0000x reference)
//
#include <hip/hip_runtime.h>
#include <stdint.h>

// R6 = R5 resubmitted verbatim (R5 bench died with "container failed twice"
// = infra acquire failure, no pytest/profile output; kernel audit found no
// alignment/OOB hazard: all vector ops 16B/8B aligned, guards correct).
// Strategy recap: 2B/entry octahedral snorm8 table (4 MB, L2-resident);
// angle_kernel 4 pairs/thread for MLP; fast_acos polynomial; vectorized
// encode. Evidence (R4 rocprof): angle 198us, HBM 13%, VALUBusy 18%,
// occ 73% -> latency-bound gather; floor ~2 L2-lines/pair ~= 70us.

typedef int            v4i  __attribute__((ext_vector_type(4)));
typedef float          v4f  __attribute__((ext_vector_type(4)));
typedef unsigned short v4s  __attribute__((ext_vector_type(4)));

__device__ __forceinline__ uint16_t oct8_encode(float x, float y, float z) {
    float s   = fabsf(x) + fabsf(y) + fabsf(z);
    float inv = 1.0f / s;                        // min ||vec|| ~1e-2 for this data
    float u = x * inv, v = y * inv;
    if (z < 0.0f) {                              // fold lower hemisphere
        float uo = (1.0f - fabsf(v)) * (u >= 0.0f ? 1.0f : -1.0f);
        float vo = (1.0f - fabsf(u)) * (v >= 0.0f ? 1.0f : -1.0f);
        u = uo; v = vo;
    }
    int iu = (int)lrintf(fminf(fmaxf(u, -1.0f), 1.0f) * 127.0f);
    int iv = (int)lrintf(fminf(fmaxf(v, -1.0f), 1.0f) * 127.0f);
    return (uint16_t)((iu & 0xff) | ((iv & 0xff) << 8));
}

__device__ __forceinline__ float3 oct8_decode(uint32_t p) {
    float u = (float)(int8_t)(p & 0xffu) * (1.0f / 127.0f);
    float v = (float)(int8_t)((p >> 8) & 0xffu) * (1.0f / 127.0f);
    float z = 1.0f - fabsf(u) - fabsf(v);
    float t = fmaxf(-z, 0.0f);                   // >0 only in lower hemisphere
    float x = u + (u >= 0.0f ? -t : t);
    float y = v + (v >= 0.0f ? -t : t);
    return make_float3(x, y, z);                 // unnormalized; fixed by rsqrt later
}

// acos via A&S 4.4.47: acos(x) = sqrt(1-x) * P(x) on [0,1], reflected for
// x<0. |poly err| <= 2e-8; sqrt via t*rsq(t) (t >= 0.05 since |x|<=0.95).
__device__ __forceinline__ float fast_acos(float x) {
    float a = fabsf(x);
    float r = fmaf(-0.0012624911f, a, 0.0066700901f);
    r = fmaf(r, a, -0.0170881256f);
    r = fmaf(r, a,  0.0308918810f);
    r = fmaf(r, a, -0.0501743046f);
    r = fmaf(r, a,  0.0889789874f);
    r = fmaf(r, a, -0.2145988016f);
    r = fmaf(r, a,  1.5707963050f);
    float t = 1.0f - a;                          // in [0.05, 1]
    r *= t * __frsqrt_rn(t);                     // sqrt(1-a), 2 instrs
    return x >= 0.0f ? r : 3.14159274f - r;
}

__device__ __forceinline__ float angle_pair(uint32_t pa, uint32_t pb) {
    float3 a = oct8_decode(pa);
    float3 b = oct8_decode(pb);
    float num = fmaf(a.x, b.x, fmaf(a.y, b.y, a.z * b.z));
    float la  = fmaf(a.x, a.x, fmaf(a.y, a.y, a.z * a.z));
    float lb  = fmaf(b.x, b.x, fmaf(b.y, b.y, b.z * b.z));
    float c   = num * __frsqrt_rn(la * lb);
    c = fminf(fmaxf(c, -1.0f), 1.0f);
    return fast_acos(0.95f * c);
}

// 4 edges/thread: 3x float4 NT loads (48B, fully coalesced) + ushort4 store.
__global__ void __launch_bounds__(256)
encode_kernel(const float* __restrict__ vec,
              uint16_t* __restrict__ tab, int E) {
    int e0 = (blockIdx.x * blockDim.x + threadIdx.x) * 4;
    if (e0 + 3 < E) {
        v4f a = __builtin_nontemporal_load((const v4f*)&vec[(size_t)e0 * 3 + 0]);
        v4f b = __builtin_nontemporal_load((const v4f*)&vec[(size_t)e0 * 3 + 4]);
        v4f c = __builtin_nontemporal_load((const v4f*)&vec[(size_t)e0 * 3 + 8]);
        v4s t;
        t.x = oct8_encode(a.x, a.y, a.z);
        t.y = oct8_encode(a.w, b.x, b.y);
        t.z = oct8_encode(b.z, b.w, c.x);
        t.w = oct8_encode(c.y, c.z, c.w);
        *(v4s*)&tab[e0] = t;                     // normal store: angle reads it from L2
    } else if (e0 < E) {
        for (int e = e0; e < E; ++e)
            tab[e] = oct8_encode(vec[3 * e + 0], vec[3 * e + 1], vec[3 * e + 2]);
    }
}

// 4 pairs/thread: 2x dwordx4 idx loads, then 8 independent 2B gathers all
// in flight before any decode/acos. 2x the in-flight line-requests of R4.
__global__ void __launch_bounds__(256)
angle_kernel(const uint16_t* __restrict__ tab,
             const int* __restrict__ src,
             const int* __restrict__ dst,
             float* __restrict__ out, int A) {
    int i = (blockIdx.x * blockDim.x + threadIdx.x) * 4;
    if (i + 3 < A) {
        v4i s4 = __builtin_nontemporal_load((const v4i*)&src[i]);
        v4i d4 = __builtin_nontemporal_load((const v4i*)&dst[i]);
        uint32_t ps0 = tab[s4.x], ps1 = tab[s4.y], ps2 = tab[s4.z], ps3 = tab[s4.w];
        uint32_t pd0 = tab[d4.x], pd1 = tab[d4.y], pd2 = tab[d4.z], pd3 = tab[d4.w];
        v4f r;
        r.x = angle_pair(ps0, pd0);
        r.y = angle_pair(ps1, pd1);
        r.z = angle_pair(ps2, pd2);
        r.w = angle_pair(ps3, pd3);
        __builtin_nontemporal_store(r, (v4f*)&out[i]);
    } else if (i < A) {
        for (int k = i; k < A; ++k)
            out[k] = angle_pair(tab[src[k]], tab[dst[k]]);
    }
}

// Fallback (workspace too small): gather raw vec + dist per endpoint.
__global__ void __launch_bounds__(256)
angle_fallback_kernel(const float* __restrict__ vec,
                      const float* __restrict__ dist,
                      const int* __restrict__ src,
                      const int* __restrict__ dst,
                      float* __restrict__ out, int A) {
    int i = blockIdx.x * blockDim.x + threadIdx.x;
    if (i >= A) return;
    int s = src[i];
    int d = dst[i];
    float sx = vec[3 * s + 0], sy = vec[3 * s + 1], sz = vec[3 * s + 2];
    float dx = vec[3 * d + 0], dy = vec[3 * d + 1], dz = vec[3 * d + 2];
    float ns = fmaxf(dist[s], 1e-5f);
    float nd = fmaxf(dist[d], 1e-5f);
    float c  = (sx * dx + sy * dy + sz * dz) / (ns * nd);
    out[i] = acosf(0.95f * c);
}

extern "C" void kernel_launch(void* const* d_in, const int* in_sizes, int n_in,
                              void* d_out, int out_size, void* d_ws, size_t ws_size,
                              hipStream_t stream) {
    const float* dist = (const float*)d_in[0];   // [E]
    const float* vec  = (const float*)d_in[1];   // [E,3]
    const int*   src  = (const int*)d_in[2];     // [A]
    const int*   dst  = (const int*)d_in[3];     // [A]
    float*       out  = (float*)d_out;           // [A]

    const int E = in_sizes[0];
    const int A = in_sizes[2];

    const int block = 256;
    if (ws_size >= (size_t)E * sizeof(uint16_t)) {
        uint16_t* tab = (uint16_t*)d_ws;
        int ethreads = (E + 3) / 4;
        encode_kernel<<<(ethreads + block - 1) / block, block, 0, stream>>>(vec, tab, E);
        int athreads = (A + 3) / 4;
        angle_kernel<<<(athreads + block - 1) / block, block, 0, stream>>>(
            tab, src, dst, out, A);
    } else {
        angle_fallback_kernel<<<(A + block - 1) / block, block, 0, stream>>>(
            vec, dist, src, dst, out, A);
    }
}